// Round 13
// baseline (228.501 us; speedup 1.0000x reference)
//
#include <hip/hip_runtime.h>
#include <math.h>

#define NN  50000
#define NE  1600000
#define NEP 500000
#define DIN 64
#define DE  32

#define BKT_SH 7                 // 128 nodes per bucket
#define NB     391               // ceil(NN / 128)
#define S1B    250               // sort blocks
#define CHK    6400              // NE / S1B
#define HB     128               // histogram blocks
#define HCHK   12500             // NE / HB (per-block per-node count small -> u8 safe)
#define HWRD   12500             // NN/4 packed u8x4 count-words
#define RB     25                // reduce blocks appended to s3: ceil(HWRD/512)
#define XWB    3125              // NN/16 xw1 blocks

// ---------------- bf16 pack/unpack helpers (RNE) ----------------
__device__ __forceinline__ unsigned f2b(float f) {
    unsigned u = __float_as_uint(f);
    return (u + 0x7FFFu + ((u >> 16) & 1u)) >> 16;
}
__device__ __forceinline__ unsigned pack2(float a, float b) {
    return f2b(a) | (f2b(b) << 16);
}
__device__ __forceinline__ float blo(unsigned u) { return __uint_as_float(u << 16); }
__device__ __forceinline__ float bhi(unsigned u) { return __uint_as_float(u & 0xFFFF0000u); }

// ---------------- H1|S1 merged: blocks [0,HB) = src histogram (u8x4); [HB,..) = dst bucket counts ----
__global__ __launch_bounds__(256) void k_h1s1(const int* __restrict__ src,
                                              const int* __restrict__ dst,
                                              unsigned* __restrict__ partial,
                                              int* __restrict__ T) {
    __shared__ unsigned h[HWRD];        // 50 KB
    int t = threadIdx.x;
    if (blockIdx.x < HB) {
        for (int i = t; i < HWRD; i += 256) h[i] = 0;
        __syncthreads();
        int beg = blockIdx.x * HCHK;
        for (int i = beg + t; i < beg + HCHK; i += 256) {
            int s = src[i];
            atomicAdd(&h[s >> 2], 1u << ((s & 3) * 8));
        }
        __syncthreads();
        unsigned* p = partial + (size_t)blockIdx.x * HWRD;
        for (int i = t; i < HWRD; i += 256) p[i] = h[i];   // coalesced, non-atomic
    } else {
        int b = blockIdx.x - HB;
        int* cd = (int*)h;
        for (int i = t; i < NB; i += 256) cd[i] = 0;
        __syncthreads();
        int beg = b * CHK;
        for (int i = beg + t; i < beg + CHK; i += 256)
            atomicAdd(&cd[dst[i] >> BKT_SH], 1);
        __syncthreads();
        for (int i = t; i < NB; i += 256) T[b * NB + i] = cd[i];
    }
}

// ---------------- S2H: single-block column scan T -> Base + BS ----------------
__global__ __launch_bounds__(512) void k_s2h(const int* __restrict__ T,
                                             int* __restrict__ Base,
                                             int* __restrict__ BS) {
    int t = threadIdx.x;
    __shared__ int tot[512];
    int run = 0;
    if (t < NB) {
        for (int b = 0; b < S1B; b++) {
            Base[b * NB + t] = run;
            run += T[b * NB + t];
        }
    }
    tot[t] = (t < NB) ? run : 0;
    __syncthreads();
    for (int off = 1; off < 512; off <<= 1) {
        int v = (t >= off) ? tot[t - off] : 0;
        __syncthreads();
        tot[t] += v;
        __syncthreads();
    }
    if (t < NB) BS[t] = (t == 0) ? 0 : tot[t - 1];
    if (t == 0) BS[NB] = NE;
}

// ---------------- S3: blocks [0,S1B) = dst-keyed sort; [S1B,S1B+RB) = u8 hist reduce -> degs ----
__global__ __launch_bounds__(512) void k_s3(const int* __restrict__ src,
                                            const int* __restrict__ dst,
                                            const int* __restrict__ T,
                                            const int* __restrict__ Base,
                                            const int* __restrict__ BS,
                                            unsigned* __restrict__ tmp,
                                            const unsigned* __restrict__ partial,
                                            int* __restrict__ degs) {
    __shared__ int scn[512];
    __shared__ int delta[NB];
    __shared__ int cur[NB];
    __shared__ unsigned buf[CHK];       // 25.6 KB
    int t = threadIdx.x;
    if (blockIdx.x >= S1B) {
        int w = (blockIdx.x - S1B) * 512 + t;
        if (w < HWRD) {
            int c0 = 0, c1 = 0, c2 = 0, c3 = 0;
            for (int b = 0; b < HB; b++) {
                unsigned v = partial[(size_t)b * HWRD + w];
                c0 += (int)(v & 0xFFu);
                c1 += (int)((v >> 8) & 0xFFu);
                c2 += (int)((v >> 16) & 0xFFu);
                c3 += (int)(v >> 24);
            }
            ((int4*)degs)[w] = make_int4(c0, c1, c2, c3);
        }
        return;
    }
    int beg = blockIdx.x * CHK;
    scn[t] = (t < NB) ? T[blockIdx.x * NB + t] : 0;
    __syncthreads();
    for (int off = 1; off < 512; off <<= 1) {
        int v = (t >= off) ? scn[t - off] : 0;
        __syncthreads();
        scn[t] += v;
        __syncthreads();
    }
    if (t < NB) {
        int ls = (t == 0) ? 0 : scn[t - 1];
        cur[t] = ls;
        delta[t] = Base[blockIdx.x * NB + t] + BS[t] - ls;
    }
    __syncthreads();
    for (int i = t; i < CHK; i += 512) {
        int d = dst[beg + i];
        int s = src[beg + i];
        int lp = atomicAdd(&cur[d >> BKT_SH], 1);
        buf[lp] = (unsigned)s | ((unsigned)d << 16);
    }
    __syncthreads();
    for (int i = t; i < CHK; i += 512) {
        unsigned e = buf[i];
        tmp[delta[e >> (16 + BKT_SH)] + i] = e;
    }
}

// ---------------- S4|XW1 merged (8 KB LDS): [0,NB) = CSR build; [NB,NB+XWB) = x@W1 ----------------
__global__ __launch_bounds__(256) void k_s4x(const unsigned* __restrict__ tmp,
                                             const int* __restrict__ BS,
                                             int* __restrict__ csr,
                                             int* __restrict__ rowptr,
                                             const float* __restrict__ x,
                                             const float* __restrict__ W1,
                                             const int* __restrict__ degs,
                                             unsigned* __restrict__ xw1b) {
    __shared__ float sW[DIN * DE];      // 8 KB union (s4 branch uses first 384 ints)
    int t = threadIdx.x;
    if (blockIdx.x < NB) {
        int* cnt = (int*)sW;
        int* scn = cnt + 128;
        int* cur = cnt + 256;
        int p = blockIdx.x;
        int ebeg = BS[p], eend = BS[p + 1];
        int ne = eend - ebeg;
        if (t < 128) cnt[t] = 0;
        __syncthreads();
        for (int i = t; i < ne; i += 256)
            atomicAdd(&cnt[(tmp[ebeg + i] >> 16) & 127], 1);
        __syncthreads();
        if (t < 128) scn[t] = cnt[t];
        __syncthreads();
        for (int off = 1; off < 128; off <<= 1) {
            int v = 0;
            if (t < 128 && t >= off) v = scn[t - off];
            __syncthreads();
            if (t < 128) scn[t] += v;
            __syncthreads();
        }
        if (t < 128) {
            int ex = (t == 0) ? 0 : scn[t - 1];
            cur[t] = ex;
            int node = (p << BKT_SH) + t;
            if (node < NN) rowptr[node] = ebeg + ex;
        }
        if (p == NB - 1 && t == 0) rowptr[NN] = NE;
        __syncthreads();
        for (int i = t; i < ne; i += 256) {
            unsigned e = tmp[ebeg + i];
            int lp = atomicAdd(&cur[(e >> 16) & 127], 1);
            csr[ebeg + lp] = (int)(e & 0xFFFFu);   // scattered within 16 KB bucket range (L2-absorbed)
        }
    } else {
        for (int i = t; i < DIN * DE; i += 256) sW[i] = W1[i];
        __syncthreads();
        int r  = (blockIdx.x - NB) * 16 + (t >> 4);
        int tc = t & 15;
        const float* xr = x + (size_t)r * DIN;
        float a0 = 0.f, a1 = 0.f;
#pragma unroll
        for (int k = 0; k < DIN; k++) {
            float v = xr[k];
            a0 += v * sW[k * DE + 2 * tc];
            a1 += v * sW[k * DE + 2 * tc + 1];
        }
        float ns = rsqrtf(fmaxf((float)degs[r], 1.0f));
        xw1b[r * 16 + tc] = pack2(a0 * ns, a1 * ns);
    }
}

// ---------------- accumulate helper ----------------
__device__ __forceinline__ void acc8(float* a, uint4 w) {
    a[0] += blo(w.x); a[1] += bhi(w.x);
    a[2] += blo(w.y); a[3] += bhi(w.y);
    a[4] += blo(w.z); a[5] += bhi(w.z);
    a[6] += blo(w.w); a[7] += bhi(w.w);
}

// ---------------- gather core: 4 lanes/row, direct csr loads (broadcast), 8-way ILP ----------------
__device__ __forceinline__ void gather_row(const int* __restrict__ csr,
                                           const uint4* __restrict__ msg,
                                           int beg, int end, int l, float* a) {
    int idx = beg;
    for (; idx + 8 <= end; idx += 8) {
        int s0 = csr[idx],     s1 = csr[idx + 1], s2 = csr[idx + 2], s3 = csr[idx + 3];
        int s4 = csr[idx + 4], s5 = csr[idx + 5], s6 = csr[idx + 6], s7 = csr[idx + 7];
        uint4 w0 = msg[s0 * 4 + l];
        uint4 w1 = msg[s1 * 4 + l];
        uint4 w2 = msg[s2 * 4 + l];
        uint4 w3 = msg[s3 * 4 + l];
        uint4 w4 = msg[s4 * 4 + l];
        uint4 w5 = msg[s5 * 4 + l];
        uint4 w6 = msg[s6 * 4 + l];
        uint4 w7 = msg[s7 * 4 + l];
        acc8(a, w0); acc8(a, w1); acc8(a, w2); acc8(a, w3);
        acc8(a, w4); acc8(a, w5); acc8(a, w6); acc8(a, w7);
    }
    for (; idx + 4 <= end; idx += 4) {
        int s0 = csr[idx], s1 = csr[idx + 1], s2 = csr[idx + 2], s3 = csr[idx + 3];
        uint4 w0 = msg[s0 * 4 + l];
        uint4 w1 = msg[s1 * 4 + l];
        uint4 w2 = msg[s2 * 4 + l];
        uint4 w3 = msg[s3 * 4 + l];
        acc8(a, w0); acc8(a, w1); acc8(a, w2); acc8(a, w3);
    }
    for (; idx < end; idx++) {
        uint4 w = msg[csr[idx] * 4 + l];
        acc8(a, w);
    }
}

// ---------------- gather layer 1: relu/bias/scale -> bf16 out ----------------
__global__ __launch_bounds__(256) void k_g1(const int* __restrict__ rowptr,
                                            const int* __restrict__ csr,
                                            const uint4* __restrict__ msg,
                                            const int* __restrict__ degs,
                                            const float* __restrict__ b1,
                                            uint4* __restrict__ out) {
    int t = blockIdx.x * 256 + threadIdx.x;
    int r = t >> 2;
    int l = t & 3;
    if (r >= NN) return;
    int beg = rowptr[r];
    int end = rowptr[r + 1];
    float a[8] = {0, 0, 0, 0, 0, 0, 0, 0};
    gather_row(csr, msg, beg, end, l, a);
    float scd = rsqrtf(fmaxf((float)(end - beg), 1.0f));
    float scs = rsqrtf(fmaxf((float)degs[r], 1.0f));
    const float4* b14 = (const float4*)b1;
    float4 bb0 = b14[2 * l], bb1 = b14[2 * l + 1];
    float o0 = fmaxf(scd * a[0] + bb0.x, 0.f) * scs;
    float o1 = fmaxf(scd * a[1] + bb0.y, 0.f) * scs;
    float o2 = fmaxf(scd * a[2] + bb0.z, 0.f) * scs;
    float o3 = fmaxf(scd * a[3] + bb0.w, 0.f) * scs;
    float o4 = fmaxf(scd * a[4] + bb1.x, 0.f) * scs;
    float o5 = fmaxf(scd * a[5] + bb1.y, 0.f) * scs;
    float o6 = fmaxf(scd * a[6] + bb1.z, 0.f) * scs;
    float o7 = fmaxf(scd * a[7] + bb1.w, 0.f) * scs;
    out[r * 4 + l] = make_uint4(pack2(o0, o1), pack2(o2, o3), pack2(o4, o5), pack2(o6, o7));
}

// ---------------- gather layer 2 + WAVE-LOCAL epilogue (W2 matmul, mu/sigma/z) ----------------
__global__ __launch_bounds__(256) void k_g2f(const int* __restrict__ rowptr,
                                             const int* __restrict__ csr,
                                             const uint4* __restrict__ msg,
                                             const float* __restrict__ W2,
                                             const float* __restrict__ b2,
                                             const float* __restrict__ eps,
                                             float* __restrict__ mu,
                                             float* __restrict__ sigma,
                                             unsigned* __restrict__ zb) {
    __shared__ float sW[DE * 64];       // 8 KB
    __shared__ float sb[64];
    int t = threadIdx.x;
    for (int i = t; i < DE * 64; i += 256) sW[i] = W2[i];
    if (t < 64) sb[t] = b2[t];
    __syncthreads();                    // only barrier: before any imbalanced work
    int g = blockIdx.x * 256 + t;
    int r = g >> 2;
    int l = g & 3;
    if (r >= NN) return;
    int beg = rowptr[r];
    int end = rowptr[r + 1];
    float a[8] = {0, 0, 0, 0, 0, 0, 0, 0};
    gather_row(csr, msg, beg, end, l, a);
    float scd = rsqrtf(fmaxf((float)(end - beg), 1.0f));
#pragma unroll
    for (int k = 0; k < 8; k++) a[k] *= scd;
    // lane l owns h2 columns [16l, 16l+16)
    int cbase = 16 * l;
    float o3[16];
#pragma unroll
    for (int j = 0; j < 16; j++) o3[j] = sb[cbase + j];
#pragma unroll
    for (int d = 0; d < 4; d++) {
        int kb = 8 * (l ^ d);           // k-block held by partner lane l^d
#pragma unroll
        for (int k = 0; k < 8; k++) {
            float av = (d == 0) ? a[k] : __shfl_xor(a[k], d);
            const float* wrow = sW + (kb + k) * 64 + cbase;
#pragma unroll
            for (int j = 0; j < 16; j++) o3[j] += av * wrow[j];
        }
    }
    // lanes 0,1: mu. lanes 2,3: sigma & z (mu fetched from partner lane l-2).
    if (l < 2) {
        float4* mp = (float4*)(mu + (size_t)r * DE + 16 * l);
        mp[0] = make_float4(o3[0],  o3[1],  o3[2],  o3[3]);
        mp[1] = make_float4(o3[4],  o3[5],  o3[6],  o3[7]);
        mp[2] = make_float4(o3[8],  o3[9],  o3[10], o3[11]);
        mp[3] = make_float4(o3[12], o3[13], o3[14], o3[15]);
    }
    float muv[16];
#pragma unroll
    for (int j = 0; j < 16; j++) muv[j] = __shfl_xor(o3[j], 2);
    if (l >= 2) {
        int cc = 16 * (l - 2);
        const float4* ep = (const float4*)(eps + (size_t)r * DE + cc);
        float4 e0 = ep[0], e1 = ep[1], e2 = ep[2], e3 = ep[3];
        float ev[16] = {e0.x, e0.y, e0.z, e0.w, e1.x, e1.y, e1.z, e1.w,
                        e2.x, e2.y, e2.z, e2.w, e3.x, e3.y, e3.z, e3.w};
        float sgv[16], zv[16];
#pragma unroll
        for (int j = 0; j < 16; j++) {
            sgv[j] = expf(0.5f * o3[j]);
            zv[j]  = muv[j] + sgv[j] * ev[j];
        }
        float4* sp = (float4*)(sigma + (size_t)r * DE + cc);
        sp[0] = make_float4(sgv[0],  sgv[1],  sgv[2],  sgv[3]);
        sp[1] = make_float4(sgv[4],  sgv[5],  sgv[6],  sgv[7]);
        sp[2] = make_float4(sgv[8],  sgv[9],  sgv[10], sgv[11]);
        sp[3] = make_float4(sgv[12], sgv[13], sgv[14], sgv[15]);
        uint4* zp = (uint4*)(zb + (size_t)r * 16 + (l - 2) * 8);
        zp[0] = make_uint4(pack2(zv[0], zv[1]), pack2(zv[2], zv[3]),
                           pack2(zv[4], zv[5]), pack2(zv[6], zv[7]));
        zp[1] = make_uint4(pack2(zv[8],  zv[9]),  pack2(zv[10], zv[11]),
                           pack2(zv[12], zv[13]), pack2(zv[14], zv[15]));
    }
}

// ---------------- merged edge dot: 2 lanes/edge, 4 independent uint4 loads per lane ----------------
__global__ __launch_bounds__(256) void k_dot2(const uint4* __restrict__ zb4,
                                              const int* __restrict__ pu,
                                              const int* __restrict__ pv,
                                              const int* __restrict__ nu,
                                              const int* __restrict__ nv,
                                              float* __restrict__ out) {
    int t = blockIdx.x * 256 + threadIdx.x;
    int e = t >> 1;
    int l = t & 1;
    if (e < 2 * NEP) {
        int ee = (e < NEP) ? e : e - NEP;
        const int* uu = (e < NEP) ? pu : nu;
        const int* vv = (e < NEP) ? pv : nv;
        int a = uu[ee];
        int b = vv[ee];
        uint4 za0 = zb4[a * 4 + 2 * l];
        uint4 za1 = zb4[a * 4 + 2 * l + 1];
        uint4 zc0 = zb4[b * 4 + 2 * l];
        uint4 zc1 = zb4[b * 4 + 2 * l + 1];
        float s = blo(za0.x) * blo(zc0.x) + bhi(za0.x) * bhi(zc0.x)
                + blo(za0.y) * blo(zc0.y) + bhi(za0.y) * bhi(zc0.y)
                + blo(za0.z) * blo(zc0.z) + bhi(za0.z) * bhi(zc0.z)
                + blo(za0.w) * blo(zc0.w) + bhi(za0.w) * bhi(zc0.w)
                + blo(za1.x) * blo(zc1.x) + bhi(za1.x) * bhi(zc1.x)
                + blo(za1.y) * blo(zc1.y) + bhi(za1.y) * bhi(zc1.y)
                + blo(za1.z) * blo(zc1.z) + bhi(za1.z) * bhi(zc1.z)
                + blo(za1.w) * blo(zc1.w) + bhi(za1.w) * bhi(zc1.w);
        s += __shfl_xor(s, 1);
        if (l == 0) out[e] = s;
    }
}

extern "C" void kernel_launch(void* const* d_in, const int* in_sizes, int n_in,
                              void* d_out, int out_size, void* d_ws, size_t ws_size,
                              hipStream_t stream) {
    const float* x    = (const float*)d_in[0];
    const float* W1   = (const float*)d_in[1];
    const float* b1   = (const float*)d_in[2];
    const float* W2   = (const float*)d_in[3];
    const float* b2   = (const float*)d_in[4];
    const float* eps  = (const float*)d_in[5];
    const int*   esrc = (const int*)d_in[6];
    const int*   edst = (const int*)d_in[7];
    const int*   psrc = (const int*)d_in[8];
    const int*   pdst = (const int*)d_in[9];
    const int*   gsrc = (const int*)d_in[10];
    const int*   gdst = (const int*)d_in[11];

    float* out = (float*)d_out;
    float* pos = out;                      // pos[NEP], neg[NEP] contiguous
    float* mu  = out + 2 * NEP;
    float* sg  = out + 2 * NEP + NN * DE;

    // ---- workspace layout (word offsets) ----
    int* wi = (int*)d_ws;
    int*      rowptr  = wi;                                   // 50001
    int*      T       = wi + 50001;                           // 97750 (counts, preserved)
    int*      Base    = wi + 147751;                          // 97750
    int*      BS      = wi + 245501;                          // 392
    int*      degs    = wi + 245896;                          // 50000 (16B-aligned for int4)
    int*      csr     = wi + 295896;                          // NE
    unsigned* partial = (unsigned*)(wi + 1895896);            // HB*HWRD = 1,600,000
    unsigned* tmp     = (unsigned*)(wi + 3495896);            // NE (own region: s4 runs with xw1)
    unsigned* P0      = (unsigned*)(wi + 5095896);            // 800000: xw1b, later zb (16B-aligned)
    unsigned* P1      = P0 + 16 * NN;                         // 800000: h1b

    k_h1s1<<<HB + S1B, 256, 0, stream>>>(esrc, edst, partial, T);
    k_s2h <<<1, 512, 0, stream>>>(T, Base, BS);
    k_s3  <<<S1B + RB, 512, 0, stream>>>(esrc, edst, T, Base, BS, tmp, partial, degs);
    k_s4x <<<NB + XWB, 256, 0, stream>>>(tmp, BS, csr, rowptr, x, W1, degs, P0);
    k_g1  <<<(NN * 4 + 255) / 256, 256, 0, stream>>>(rowptr, csr, (const uint4*)P0, degs, b1, (uint4*)P1);
    k_g2f <<<(NN * 4 + 255) / 256, 256, 0, stream>>>(rowptr, csr, (const uint4*)P1, W2, b2, eps, mu, sg, P0);
    k_dot2<<<(2 * NEP * 2 + 255) / 256, 256, 0, stream>>>((const uint4*)P0, psrc, pdst, gsrc, gdst, pos);
}

// Round 14
// 218.378 us; speedup vs baseline: 1.0464x; 1.0464x over previous
//
#include <hip/hip_runtime.h>
#include <math.h>

#define NN  50000
#define NE  1600000
#define NEP 500000
#define DIN 64
#define DE  32

#define BKT_SH 7                 // 128 nodes per bucket
#define NB     391               // ceil(NN / 128)
#define S1B    250               // sort blocks
#define CHK    6400              // NE / S1B
#define HB     128               // histogram blocks
#define HCHK   12500             // NE / HB (per-block per-node count small -> u8 safe)
#define HWRD   12500             // NN/4 packed u8x4 count-words
#define XWB    3125              // NN/16 xw1 blocks

// ---------------- bf16 pack/unpack helpers (RNE) ----------------
__device__ __forceinline__ unsigned f2b(float f) {
    unsigned u = __float_as_uint(f);
    return (u + 0x7FFFu + ((u >> 16) & 1u)) >> 16;
}
__device__ __forceinline__ unsigned pack2(float a, float b) {
    return f2b(a) | (f2b(b) << 16);
}
__device__ __forceinline__ float blo(unsigned u) { return __uint_as_float(u << 16); }
__device__ __forceinline__ float bhi(unsigned u) { return __uint_as_float(u & 0xFFFF0000u); }

// ---------------- H1|S1 merged: blocks [0,HB) = src histogram (u8x4); [HB,..) = dst bucket counts ----
__global__ __launch_bounds__(256) void k_h1s1(const int* __restrict__ src,
                                              const int* __restrict__ dst,
                                              unsigned* __restrict__ partial,
                                              int* __restrict__ T) {
    __shared__ unsigned h[HWRD];        // 50 KB
    int t = threadIdx.x;
    if (blockIdx.x < HB) {
        for (int i = t; i < HWRD; i += 256) h[i] = 0;
        __syncthreads();
        int beg = blockIdx.x * HCHK;
        for (int i = beg + t; i < beg + HCHK; i += 256) {
            int s = src[i];
            atomicAdd(&h[s >> 2], 1u << ((s & 3) * 8));
        }
        __syncthreads();
        unsigned* p = partial + (size_t)blockIdx.x * HWRD;
        for (int i = t; i < HWRD; i += 256) p[i] = h[i];   // coalesced, non-atomic
    } else {
        int b = blockIdx.x - HB;
        int* cd = (int*)h;
        for (int i = t; i < NB; i += 256) cd[i] = 0;
        __syncthreads();
        int beg = b * CHK;
        for (int i = beg + t; i < beg + CHK; i += 256)
            atomicAdd(&cd[dst[i] >> BKT_SH], 1);
        __syncthreads();
        for (int i = t; i < NB; i += 256) T[b * NB + i] = cd[i];
    }
}

// ---------------- S2H: block0 = column scan T -> Base + BS; blocks 1.. = u8 hist reduce -> degs ----
__global__ __launch_bounds__(512) void k_s2h(const int* __restrict__ T,
                                             int* __restrict__ Base,
                                             int* __restrict__ BS,
                                             const unsigned* __restrict__ partial,
                                             int* __restrict__ degs) {
    int t = threadIdx.x;
    if (blockIdx.x == 0) {
        __shared__ int tot[512];
        int run = 0;
        if (t < NB) {
            for (int b = 0; b < S1B; b++) {
                Base[b * NB + t] = run;
                run += T[b * NB + t];
            }
        }
        tot[t] = (t < NB) ? run : 0;
        __syncthreads();
        for (int off = 1; off < 512; off <<= 1) {
            int v = (t >= off) ? tot[t - off] : 0;
            __syncthreads();
            tot[t] += v;
            __syncthreads();
        }
        if (t < NB) BS[t] = (t == 0) ? 0 : tot[t - 1];
        if (t == 0) BS[NB] = NE;
    } else {
        int w = (blockIdx.x - 1) * 512 + t;
        if (w < HWRD) {
            int c0 = 0, c1 = 0, c2 = 0, c3 = 0;
            for (int b = 0; b < HB; b++) {
                unsigned v = partial[(size_t)b * HWRD + w];
                c0 += (int)(v & 0xFFu);
                c1 += (int)((v >> 8) & 0xFFu);
                c2 += (int)((v >> 16) & 0xFFu);
                c3 += (int)(v >> 24);
            }
            ((int4*)degs)[w] = make_int4(c0, c1, c2, c3);
        }
    }
}

// ---------------- S3: dst-keyed block-local sort; counts preloaded from T ----------------
__global__ __launch_bounds__(512) void k_s3(const int* __restrict__ src,
                                            const int* __restrict__ dst,
                                            const int* __restrict__ T,
                                            const int* __restrict__ Base,
                                            const int* __restrict__ BS,
                                            unsigned* __restrict__ tmp) {
    __shared__ int scn[512];
    __shared__ int delta[NB];
    __shared__ int cur[NB];
    __shared__ unsigned buf[CHK];       // 25.6 KB
    int t = threadIdx.x;
    int beg = blockIdx.x * CHK;
    scn[t] = (t < NB) ? T[blockIdx.x * NB + t] : 0;
    __syncthreads();
    for (int off = 1; off < 512; off <<= 1) {
        int v = (t >= off) ? scn[t - off] : 0;
        __syncthreads();
        scn[t] += v;
        __syncthreads();
    }
    if (t < NB) {
        int ls = (t == 0) ? 0 : scn[t - 1];
        cur[t] = ls;
        delta[t] = Base[blockIdx.x * NB + t] + BS[t] - ls;
    }
    __syncthreads();
    for (int i = t; i < CHK; i += 512) {
        int d = dst[beg + i];
        int s = src[beg + i];
        int lp = atomicAdd(&cur[d >> BKT_SH], 1);
        buf[lp] = (unsigned)s | ((unsigned)d << 16);
    }
    __syncthreads();
    for (int i = t; i < CHK; i += 512) {
        unsigned e = buf[i];
        tmp[delta[e >> (16 + BKT_SH)] + i] = e;
    }
}

// ---------------- S4|XW1 merged (8 KB LDS): [0,NB) = CSR build; [NB,NB+XWB) = x@W1 ----------------
__global__ __launch_bounds__(256) void k_s4x(const unsigned* __restrict__ tmp,
                                             const int* __restrict__ BS,
                                             int* __restrict__ csr,
                                             int* __restrict__ rowptr,
                                             const float* __restrict__ x,
                                             const float* __restrict__ W1,
                                             const int* __restrict__ degs,
                                             unsigned* __restrict__ xw1b) {
    __shared__ float sW[DIN * DE];      // 8 KB union (s4 branch uses first 384 ints)
    int t = threadIdx.x;
    if (blockIdx.x < NB) {
        int* cnt = (int*)sW;
        int* scn = cnt + 128;
        int* cur = cnt + 256;
        int p = blockIdx.x;
        int ebeg = BS[p], eend = BS[p + 1];
        int ne = eend - ebeg;
        if (t < 128) cnt[t] = 0;
        __syncthreads();
        for (int i = t; i < ne; i += 256)
            atomicAdd(&cnt[(tmp[ebeg + i] >> 16) & 127], 1);
        __syncthreads();
        if (t < 128) scn[t] = cnt[t];
        __syncthreads();
        for (int off = 1; off < 128; off <<= 1) {
            int v = 0;
            if (t < 128 && t >= off) v = scn[t - off];
            __syncthreads();
            if (t < 128) scn[t] += v;
            __syncthreads();
        }
        if (t < 128) {
            int ex = (t == 0) ? 0 : scn[t - 1];
            cur[t] = ex;
            int node = (p << BKT_SH) + t;
            if (node < NN) rowptr[node] = ebeg + ex;
        }
        if (p == NB - 1 && t == 0) rowptr[NN] = NE;
        __syncthreads();
        for (int i = t; i < ne; i += 256) {
            unsigned e = tmp[ebeg + i];
            int lp = atomicAdd(&cur[(e >> 16) & 127], 1);
            csr[ebeg + lp] = (int)(e & 0xFFFFu);   // scattered within 16 KB bucket range (L2-absorbed)
        }
    } else {
        for (int i = t; i < DIN * DE; i += 256) sW[i] = W1[i];
        __syncthreads();
        int r  = (blockIdx.x - NB) * 16 + (t >> 4);
        int tc = t & 15;
        const float* xr = x + (size_t)r * DIN;
        float a0 = 0.f, a1 = 0.f;
#pragma unroll
        for (int k = 0; k < DIN; k++) {
            float v = xr[k];
            a0 += v * sW[k * DE + 2 * tc];
            a1 += v * sW[k * DE + 2 * tc + 1];
        }
        float ns = rsqrtf(fmaxf((float)degs[r], 1.0f));
        xw1b[r * 16 + tc] = pack2(a0 * ns, a1 * ns);
    }
}

// ---------------- accumulate helper ----------------
__device__ __forceinline__ void acc8(float* a, uint4 w) {
    a[0] += blo(w.x); a[1] += bhi(w.x);
    a[2] += blo(w.y); a[3] += bhi(w.y);
    a[4] += blo(w.z); a[5] += bhi(w.z);
    a[6] += blo(w.w); a[7] += bhi(w.w);
}

// ---------------- gather core: 4 lanes/row, direct csr loads (broadcast), 8-way ILP ----------------
__device__ __forceinline__ void gather_row(const int* __restrict__ csr,
                                           const uint4* __restrict__ msg,
                                           int beg, int end, int l, float* a) {
    int idx = beg;
    for (; idx + 8 <= end; idx += 8) {
        int s0 = csr[idx],     s1 = csr[idx + 1], s2 = csr[idx + 2], s3 = csr[idx + 3];
        int s4 = csr[idx + 4], s5 = csr[idx + 5], s6 = csr[idx + 6], s7 = csr[idx + 7];
        uint4 w0 = msg[s0 * 4 + l];
        uint4 w1 = msg[s1 * 4 + l];
        uint4 w2 = msg[s2 * 4 + l];
        uint4 w3 = msg[s3 * 4 + l];
        uint4 w4 = msg[s4 * 4 + l];
        uint4 w5 = msg[s5 * 4 + l];
        uint4 w6 = msg[s6 * 4 + l];
        uint4 w7 = msg[s7 * 4 + l];
        acc8(a, w0); acc8(a, w1); acc8(a, w2); acc8(a, w3);
        acc8(a, w4); acc8(a, w5); acc8(a, w6); acc8(a, w7);
    }
    for (; idx + 4 <= end; idx += 4) {
        int s0 = csr[idx], s1 = csr[idx + 1], s2 = csr[idx + 2], s3 = csr[idx + 3];
        uint4 w0 = msg[s0 * 4 + l];
        uint4 w1 = msg[s1 * 4 + l];
        uint4 w2 = msg[s2 * 4 + l];
        uint4 w3 = msg[s3 * 4 + l];
        acc8(a, w0); acc8(a, w1); acc8(a, w2); acc8(a, w3);
    }
    for (; idx < end; idx++) {
        uint4 w = msg[csr[idx] * 4 + l];
        acc8(a, w);
    }
}

// ---------------- gather layer 1: relu/bias/scale -> bf16 out ----------------
__global__ __launch_bounds__(256) void k_g1(const int* __restrict__ rowptr,
                                            const int* __restrict__ csr,
                                            const uint4* __restrict__ msg,
                                            const int* __restrict__ degs,
                                            const float* __restrict__ b1,
                                            uint4* __restrict__ out) {
    int t = blockIdx.x * 256 + threadIdx.x;
    int r = t >> 2;
    int l = t & 3;
    if (r >= NN) return;
    int beg = rowptr[r];
    int end = rowptr[r + 1];
    float a[8] = {0, 0, 0, 0, 0, 0, 0, 0};
    gather_row(csr, msg, beg, end, l, a);
    float scd = rsqrtf(fmaxf((float)(end - beg), 1.0f));
    float scs = rsqrtf(fmaxf((float)degs[r], 1.0f));
    const float4* b14 = (const float4*)b1;
    float4 bb0 = b14[2 * l], bb1 = b14[2 * l + 1];
    float o0 = fmaxf(scd * a[0] + bb0.x, 0.f) * scs;
    float o1 = fmaxf(scd * a[1] + bb0.y, 0.f) * scs;
    float o2 = fmaxf(scd * a[2] + bb0.z, 0.f) * scs;
    float o3 = fmaxf(scd * a[3] + bb0.w, 0.f) * scs;
    float o4 = fmaxf(scd * a[4] + bb1.x, 0.f) * scs;
    float o5 = fmaxf(scd * a[5] + bb1.y, 0.f) * scs;
    float o6 = fmaxf(scd * a[6] + bb1.z, 0.f) * scs;
    float o7 = fmaxf(scd * a[7] + bb1.w, 0.f) * scs;
    out[r * 4 + l] = make_uint4(pack2(o0, o1), pack2(o2, o3), pack2(o4, o5), pack2(o6, o7));
}

// ---------------- gather layer 2 + WAVE-LOCAL epilogue (W2 matmul, mu/sigma/z) ----------------
__global__ __launch_bounds__(256) void k_g2f(const int* __restrict__ rowptr,
                                             const int* __restrict__ csr,
                                             const uint4* __restrict__ msg,
                                             const float* __restrict__ W2,
                                             const float* __restrict__ b2,
                                             const float* __restrict__ eps,
                                             float* __restrict__ mu,
                                             float* __restrict__ sigma,
                                             unsigned* __restrict__ zb) {
    __shared__ float sW[DE * 64];       // 8 KB
    __shared__ float sb[64];
    int t = threadIdx.x;
    for (int i = t; i < DE * 64; i += 256) sW[i] = W2[i];
    if (t < 64) sb[t] = b2[t];
    __syncthreads();                    // only barrier: before any imbalanced work
    int g = blockIdx.x * 256 + t;
    int r = g >> 2;
    int l = g & 3;
    if (r >= NN) return;
    int beg = rowptr[r];
    int end = rowptr[r + 1];
    float a[8] = {0, 0, 0, 0, 0, 0, 0, 0};
    gather_row(csr, msg, beg, end, l, a);
    float scd = rsqrtf(fmaxf((float)(end - beg), 1.0f));
#pragma unroll
    for (int k = 0; k < 8; k++) a[k] *= scd;
    // lane l owns h2 columns [16l, 16l+16)
    int cbase = 16 * l;
    float o3[16];
#pragma unroll
    for (int j = 0; j < 16; j++) o3[j] = sb[cbase + j];
#pragma unroll
    for (int d = 0; d < 4; d++) {
        int kb = 8 * (l ^ d);           // k-block held by partner lane l^d
#pragma unroll
        for (int k = 0; k < 8; k++) {
            float av = (d == 0) ? a[k] : __shfl_xor(a[k], d);
            const float* wrow = sW + (kb + k) * 64 + cbase;
#pragma unroll
            for (int j = 0; j < 16; j++) o3[j] += av * wrow[j];
        }
    }
    // lanes 0,1: mu. lanes 2,3: sigma & z (mu fetched from partner lane l-2).
    if (l < 2) {
        float4* mp = (float4*)(mu + (size_t)r * DE + 16 * l);
        mp[0] = make_float4(o3[0],  o3[1],  o3[2],  o3[3]);
        mp[1] = make_float4(o3[4],  o3[5],  o3[6],  o3[7]);
        mp[2] = make_float4(o3[8],  o3[9],  o3[10], o3[11]);
        mp[3] = make_float4(o3[12], o3[13], o3[14], o3[15]);
    }
    float muv[16];
#pragma unroll
    for (int j = 0; j < 16; j++) muv[j] = __shfl_xor(o3[j], 2);
    if (l >= 2) {
        int cc = 16 * (l - 2);
        const float4* ep = (const float4*)(eps + (size_t)r * DE + cc);
        float4 e0 = ep[0], e1 = ep[1], e2 = ep[2], e3 = ep[3];
        float ev[16] = {e0.x, e0.y, e0.z, e0.w, e1.x, e1.y, e1.z, e1.w,
                        e2.x, e2.y, e2.z, e2.w, e3.x, e3.y, e3.z, e3.w};
        float sgv[16], zv[16];
#pragma unroll
        for (int j = 0; j < 16; j++) {
            sgv[j] = expf(0.5f * o3[j]);
            zv[j]  = muv[j] + sgv[j] * ev[j];
        }
        float4* sp = (float4*)(sigma + (size_t)r * DE + cc);
        sp[0] = make_float4(sgv[0],  sgv[1],  sgv[2],  sgv[3]);
        sp[1] = make_float4(sgv[4],  sgv[5],  sgv[6],  sgv[7]);
        sp[2] = make_float4(sgv[8],  sgv[9],  sgv[10], sgv[11]);
        sp[3] = make_float4(sgv[12], sgv[13], sgv[14], sgv[15]);
        uint4* zp = (uint4*)(zb + (size_t)r * 16 + (l - 2) * 8);
        zp[0] = make_uint4(pack2(zv[0], zv[1]), pack2(zv[2], zv[3]),
                           pack2(zv[4], zv[5]), pack2(zv[6], zv[7]));
        zp[1] = make_uint4(pack2(zv[8],  zv[9]),  pack2(zv[10], zv[11]),
                           pack2(zv[12], zv[13]), pack2(zv[14], zv[15]));
    }
}

// ---------------- merged edge dot: 4 lanes/edge, one uint4/lane (one coalesced line per row) ----
__global__ __launch_bounds__(256) void k_dot2(const uint4* __restrict__ zb4,
                                              const int* __restrict__ pu,
                                              const int* __restrict__ pv,
                                              const int* __restrict__ nu,
                                              const int* __restrict__ nv,
                                              float* __restrict__ out) {
    int t = blockIdx.x * 256 + threadIdx.x;
    int e = t >> 2;
    int l = t & 3;
    if (e < 2 * NEP) {
        int ee = (e < NEP) ? e : e - NEP;
        const int* uu = (e < NEP) ? pu : nu;
        const int* vv = (e < NEP) ? pv : nv;
        int a = uu[ee];
        int b = vv[ee];
        uint4 za = zb4[a * 4 + l];
        uint4 zc = zb4[b * 4 + l];
        float s = blo(za.x) * blo(zc.x) + bhi(za.x) * bhi(zc.x)
                + blo(za.y) * blo(zc.y) + bhi(za.y) * bhi(zc.y)
                + blo(za.z) * blo(zc.z) + bhi(za.z) * bhi(zc.z)
                + blo(za.w) * blo(zc.w) + bhi(za.w) * bhi(zc.w);
        s += __shfl_xor(s, 1);
        s += __shfl_xor(s, 2);
        if (l == 0) out[e] = s;
    }
}

extern "C" void kernel_launch(void* const* d_in, const int* in_sizes, int n_in,
                              void* d_out, int out_size, void* d_ws, size_t ws_size,
                              hipStream_t stream) {
    const float* x    = (const float*)d_in[0];
    const float* W1   = (const float*)d_in[1];
    const float* b1   = (const float*)d_in[2];
    const float* W2   = (const float*)d_in[3];
    const float* b2   = (const float*)d_in[4];
    const float* eps  = (const float*)d_in[5];
    const int*   esrc = (const int*)d_in[6];
    const int*   edst = (const int*)d_in[7];
    const int*   psrc = (const int*)d_in[8];
    const int*   pdst = (const int*)d_in[9];
    const int*   gsrc = (const int*)d_in[10];
    const int*   gdst = (const int*)d_in[11];

    float* out = (float*)d_out;
    float* pos = out;                      // pos[NEP], neg[NEP] contiguous
    float* mu  = out + 2 * NEP;
    float* sg  = out + 2 * NEP + NN * DE;

    // ---- workspace layout (word offsets) ----
    int* wi = (int*)d_ws;
    int*      rowptr  = wi;                                   // 50001
    int*      T       = wi + 50001;                           // 97750 (counts, preserved)
    int*      Base    = wi + 147751;                          // 97750
    int*      BS      = wi + 245501;                          // 392
    int*      degs    = wi + 245896;                          // 50000 (16B-aligned for int4)
    int*      csr     = wi + 295896;                          // NE
    unsigned* partial = (unsigned*)(wi + 1895896);            // HB*HWRD = 1,600,000
    unsigned* tmp     = (unsigned*)(wi + 3495896);            // NE (own region: s4 runs with xw1)
    unsigned* P0      = (unsigned*)(wi + 5095896);            // 800000: xw1b, later zb (16B-aligned)
    unsigned* P1      = P0 + 16 * NN;                         // 800000: h1b

    k_h1s1<<<HB + S1B, 256, 0, stream>>>(esrc, edst, partial, T);
    k_s2h <<<1 + (HWRD + 511) / 512, 512, 0, stream>>>(T, Base, BS, partial, degs);
    k_s3  <<<S1B, 512, 0, stream>>>(esrc, edst, T, Base, BS, tmp);
    k_s4x <<<NB + XWB, 256, 0, stream>>>(tmp, BS, csr, rowptr, x, W1, degs, P0);
    k_g1  <<<(NN * 4 + 255) / 256, 256, 0, stream>>>(rowptr, csr, (const uint4*)P0, degs, b1, (uint4*)P1);
    k_g2f <<<(NN * 4 + 255) / 256, 256, 0, stream>>>(rowptr, csr, (const uint4*)P1, W2, b2, eps, mu, sg, P0);
    k_dot2<<<(2 * NEP * 4 + 255) / 256, 256, 0, stream>>>((const uint4*)P0, psrc, pdst, gsrc, gdst, pos);
}